// Round 2
// baseline (195.077 us; speedup 1.0000x reference)
//
#include <hip/hip_runtime.h>
#include <math.h>

#define NG 9
#define TILE 256
#define GX 16
#define GY 64

__device__ __forceinline__ float softplus_f(float x) {
    // stable: max(x,0) + log1p(exp(-|x|))
    float e = __expf(-fabsf(x));
    return fmaxf(x, 0.f) + __logf(1.f + e);
}

// cnts: [0]=nT, [1]=nN, [2..10]=cT[g], [11..19]=cN[g]
__global__ __launch_bounds__(256) void k_prep(
    const float* __restrict__ logits, const float* __restrict__ ytox,
    const float* __restrict__ yid, int B,
    float* __restrict__ Tlog, int* __restrict__ Tmask,
    float* __restrict__ Nlog, int* __restrict__ Nmask,
    int* __restrict__ cnts) {
    int i = blockIdx.x * blockDim.x + threadIdx.x;
    if (i >= B) return;
    float l = logits[i];
    bool tox = ytox[i] >= 0.5f;
    int m = 0;
#pragma unroll
    for (int g = 0; g < NG; ++g)
        if (yid[i * NG + g] >= 0.5f) m |= (1 << g);
    if (tox) {
        int p = atomicAdd(&cnts[0], 1);
        Tlog[p] = l; Tmask[p] = m;
#pragma unroll
        for (int g = 0; g < NG; ++g)
            if ((m >> g) & 1) atomicAdd(&cnts[2 + g], 1);
    } else {
        int p = atomicAdd(&cnts[1], 1);
        Nlog[p] = l; Nmask[p] = m;
#pragma unroll
        for (int g = 0; g < NG; ++g)
            if ((m >> g) & 1) atomicAdd(&cnts[2 + NG + g], 1);
    }
}

// Pairs + fused finalize (last block via ticket).
// num layout: num[t*NG+g] fp64.
__global__ __launch_bounds__(256) void k_main(
    const float* __restrict__ Tlog, const int* __restrict__ Tmask,
    const float* __restrict__ Nlog, const int* __restrict__ Nmask,
    const int* __restrict__ cnts, double* __restrict__ num,
    int* __restrict__ done, float* __restrict__ out) {
    __shared__ float sl[TILE];
    __shared__ int   smk[TILE];
    __shared__ float red[4][3 * NG];
    __shared__ int   sticket;

    const int nT = cnts[0], nN = cnts[1];
    const int tid = threadIdx.x;
    const int per  = (nN + GY - 1) / GY;      // j's per y-block
    const int jBeg = blockIdx.y * per;
    const int jEnd = min(nN, jBeg + per);

    // grid-stride over i-chunks: every block stays busy regardless of nT
    for (int ic = blockIdx.x; ic * 256 < nT; ic += GX) {
        const int i = ic * 256 + tid;
        const bool active = i < nT;
        const float li = active ? Tlog[i] : 0.f;
        const int   mi = active ? Tmask[i] : 0;

        float Rall = 0.f;
        float Rg[NG];
#pragma unroll
        for (int g = 0; g < NG; ++g) Rg[g] = 0.f;

        for (int t = jBeg; t < jEnd; t += TILE) {
            const int n = min(TILE, jEnd - t);
            __syncthreads();
            if (tid < n) { sl[tid] = Nlog[t + tid]; smk[tid] = Nmask[t + tid]; }
            __syncthreads();
#pragma unroll 4
            for (int k = 0; k < n; ++k) {
                const float lj = sl[k];                                   // LDS broadcast
                const int   mj = __builtin_amdgcn_readfirstlane(smk[k]);  // wave-uniform -> SGPR
                const float s = softplus_f(lj - li);
                Rall += s;
#pragma unroll
                for (int g = 0; g < NG; ++g) {
                    const float bg = ((mj >> g) & 1) ? 1.0f : 0.0f;  // scalar cselect
                    Rg[g] = fmaf(bg, s, Rg[g]);                      // v_fmac w/ SGPR src
                }
            }
        }

        // fold into 27 partials (zero for inactive lanes: Rg/Rall already 0 path)
        float v[3 * NG];
#pragma unroll
        for (int g = 0; g < NG; ++g) {
            const bool a = active && ((mi >> g) & 1);
            const float rg = active ? Rg[g] : 0.f;
            const float ra = active ? Rall : 0.f;
            v[g]          = a ? rg : 0.f;          // t=0: i in Tg, j in Ng
            v[NG + g]     = a ? 0.f : rg;          // t=1: i toxic not in g, j in Ng
            v[2 * NG + g] = a ? (ra - rg) : 0.f;   // t=2: i in Tg, j not in Ng
        }
        const int lane = tid & 63;
        const int wave = tid >> 6;
#pragma unroll
        for (int r = 0; r < 3 * NG; ++r) {
            float x = v[r];
#pragma unroll
            for (int off = 32; off > 0; off >>= 1)
                x += __shfl_xor(x, off, 64);
            if (lane == 0) red[wave][r] = x;
        }
        __syncthreads();
        if (tid < 3 * NG) {
            float s = red[0][tid] + red[1][tid] + red[2][tid] + red[3][tid];
            atomicAdd(&num[tid], (double)s);
        }
        __syncthreads();   // protect red reuse on next chunk
    }

    // ---- ticket: last block finalizes ----
    __threadfence();
    if (tid == 0) sticket = atomicAdd(done, 1);
    __syncthreads();
    if (sticket == GX * GY - 1 && tid == 0) {
        double nm[3 * NG];
        for (int r = 0; r < 3 * NG; ++r) nm[r] = atomicAdd(&num[r], 0.0); // coherent read
        const long long nTt = cnts[0], nNt = cnts[1];
        double acc = 0.0; int ngv = 0;
        for (int g = 0; g < NG; ++g) {
            const long long cT = cnts[2 + g], cN = cnts[2 + NG + g];
            const long long c0 = cT * cN;
            const long long c1 = (nTt - cT) * cN;
            const long long c2 = cT * (nNt - cN);
            const double t0 = nm[g]          / (double)(c0 > 0 ? c0 : 1);
            const double t1 = nm[NG + g]     / (double)(c1 > 0 ? c1 : 1);
            const double t2 = nm[2 * NG + g] / (double)(c2 > 0 ? c2 : 1);
            const int nv = (c0 > 0) + (c1 > 0) + (c2 > 0);
            const double gl = ((c0 > 0 ? t0 : 0.0) + (c1 > 0 ? t1 : 0.0) +
                               (c2 > 0 ? t2 : 0.0)) / (double)(nv > 0 ? nv : 1);
            if (nv > 0) { const double g2 = gl * gl; acc += g2 * g2; ++ngv; }
        }
        const double mean_p = acc / (double)(ngv > 0 ? ngv : 1);
        const double loss = pow(mean_p, 0.25);
        out[0] = (float)(ngv > 0 ? loss : 0.0);
    }
}

extern "C" void kernel_launch(void* const* d_in, const int* in_sizes, int n_in,
                              void* d_out, int out_size, void* d_ws, size_t ws_size,
                              hipStream_t stream) {
    const float* logits = (const float*)d_in[0];
    const float* ytox   = (const float*)d_in[1];
    const float* yid    = (const float*)d_in[2];
    const int B = in_sizes[0];

    char* ws = (char*)d_ws;
    double* num  = (double*)ws;                    // 27 doubles
    int*    cnts = (int*)(ws + 256);               // 20 ints
    int*    done = (int*)(ws + 448);               // ticket counter
    float*  Tlog  = (float*)(ws + 512);
    int*    Tmask = (int*)(ws + 512 + 4 * (size_t)B);
    float*  Nlog  = (float*)(ws + 512 + 8 * (size_t)B);
    int*    Nmask = (int*)(ws + 512 + 12 * (size_t)B);

    hipMemsetAsync(d_ws, 0, 512, stream);          // zero num + cnts + done

    k_prep<<<dim3((B + 255) / 256), dim3(256), 0, stream>>>(
        logits, ytox, yid, B, Tlog, Tmask, Nlog, Nmask, cnts);

    k_main<<<dim3(GX, GY), dim3(256), 0, stream>>>(
        Tlog, Tmask, Nlog, Nmask, cnts, num, done, (float*)d_out);
}

// Round 3
// 187.729 us; speedup vs baseline: 1.0391x; 1.0391x over previous
//
#include <hip/hip_runtime.h>
#include <math.h>

#define NG 9
#define NR 27            // 3*NG partial sums
#define TILE 128
#define GXL 4            // x-blocks (i-chunks of 1024 i's, grid-stride)
#define GY 64            // y-blocks (j-chunks)
#define NBLK (GXL * GY)
#define IB 4             // i's per thread

__device__ __forceinline__ float softplus_f(float x) {
    // stable: max(x,0) + log1p(exp(-|x|))
    float e = __expf(-fabsf(x));
    return fmaxf(x, 0.f) + __logf(1.f + e);
}

// cnts: [0]=nT, [1]=nN, [2..10]=cT[g], [11..19]=cN[g]
__global__ __launch_bounds__(256) void k_prep(
    const float* __restrict__ logits, const float* __restrict__ ytox,
    const float* __restrict__ yid, int B,
    float* __restrict__ Tlog, int* __restrict__ Tmask,
    float* __restrict__ Nlog, int* __restrict__ Nmask,
    int* __restrict__ cnts) {
    int i = blockIdx.x * blockDim.x + threadIdx.x;
    if (i >= B) return;
    float l = logits[i];
    bool tox = ytox[i] >= 0.5f;
    int m = 0;
#pragma unroll
    for (int g = 0; g < NG; ++g)
        if (yid[i * NG + g] >= 0.5f) m |= (1 << g);
    if (tox) {
        int p = atomicAdd(&cnts[0], 1);
        Tlog[p] = l; Tmask[p] = m;
#pragma unroll
        for (int g = 0; g < NG; ++g)
            if ((m >> g) & 1) atomicAdd(&cnts[2 + g], 1);
    } else {
        int p = atomicAdd(&cnts[1], 1);
        Nlog[p] = l; Nmask[p] = m;
#pragma unroll
        for (int g = 0; g < NG; ++g)
            if ((m >> g) & 1) atomicAdd(&cnts[2 + NG + g], 1);
    }
}

// Pairs, register-blocked IB=4, per-block fp32 partials, ticketed finalize.
__global__ __launch_bounds__(256) void k_main(
    const float* __restrict__ Tlog, const int* __restrict__ Tmask,
    const float* __restrict__ Nlog, const int* __restrict__ Nmask,
    const int* __restrict__ cnts, float* __restrict__ part,
    int* __restrict__ done, float* __restrict__ out) {
    __shared__ float sl[TILE];
    __shared__ int   smk[TILE];
    __shared__ float red[4][NR];
    __shared__ int   sticket;
    __shared__ double fin[NR];

    const int nT = cnts[0], nN = cnts[1];
    const int tid  = threadIdx.x;
    const int lane = tid & 63, wave = tid >> 6;
    const int per  = (nN + GY - 1) / GY;
    const int jBeg = blockIdx.y * per;
    const int jEnd = min(nN, jBeg + per);

    if (tid < NR) { red[0][tid] = 0.f; red[1][tid] = 0.f; red[2][tid] = 0.f; red[3][tid] = 0.f; }
    __syncthreads();

    // grid-stride over i-chunks of 256*IB; bounds are block-uniform (no divergent barriers)
    for (int ic = blockIdx.x; ic * (256 * IB) < nT; ic += GXL) {
        const int ibase = ic * (256 * IB) + tid * IB;
        float li[IB]; int mi[IB]; bool act[IB];
#pragma unroll
        for (int u = 0; u < IB; ++u) {
            const int i = ibase + u;
            act[u] = (i < nT);
            li[u] = act[u] ? Tlog[i]  : 0.f;   // contiguous 4/thread -> dwordx4
            mi[u] = act[u] ? Tmask[i] : 0;
        }

        float Rall[IB];
        float Rg[IB][NG];
#pragma unroll
        for (int u = 0; u < IB; ++u) {
            Rall[u] = 0.f;
#pragma unroll
            for (int g = 0; g < NG; ++g) Rg[u][g] = 0.f;
        }

        for (int t = jBeg; t < jEnd; t += TILE) {
            const int n = min(TILE, jEnd - t);
            __syncthreads();
            if (tid < n) { sl[tid] = Nlog[t + tid]; smk[tid] = Nmask[t + tid]; }
            __syncthreads();
#pragma unroll 4
            for (int k = 0; k < n; ++k) {
                const float lj = sl[k];                                   // LDS broadcast
                const int   mj = __builtin_amdgcn_readfirstlane(smk[k]);  // uniform -> SGPR
                float s[IB];
#pragma unroll
                for (int u = 0; u < IB; ++u) {
                    s[u] = softplus_f(lj - li[u]);   // 4 independent trans chains (ILP)
                    Rall[u] += s[u];
                }
#pragma unroll
                for (int g = 0; g < NG; ++g) {
                    const float bg = ((mj >> g) & 1) ? 1.0f : 0.0f;  // SGPR cselect
#pragma unroll
                    for (int u = 0; u < IB; ++u)
                        Rg[u][g] = fmaf(bg, s[u], Rg[u][g]);          // v_fmac w/ SGPR src
                }
            }
        }

        // fold IB i's into 27 partials
        float v[NR];
#pragma unroll
        for (int r = 0; r < NR; ++r) v[r] = 0.f;
#pragma unroll
        for (int u = 0; u < IB; ++u) {
            const float ra = act[u] ? Rall[u] : 0.f;
#pragma unroll
            for (int g = 0; g < NG; ++g) {
                const float rg = act[u] ? Rg[u][g] : 0.f;
                const bool a = (mi[u] >> g) & 1;
                v[g]          += a ? rg : 0.f;        // t=0: i in Tg, j in Ng
                v[NG + g]     += a ? 0.f : rg;        // t=1: i toxic !in g, j in Ng
                v[2 * NG + g] += a ? (ra - rg) : 0.f; // t=2: i in Tg, j !in Ng
            }
        }
        // wave reduce, accumulate per-wave rows (lane0 only writer of its row)
#pragma unroll
        for (int r = 0; r < NR; ++r) {
            float x = v[r];
#pragma unroll
            for (int off = 32; off > 0; off >>= 1)
                x += __shfl_xor(x, off, 64);
            if (lane == 0) red[wave][r] += x;
        }
    }

    __syncthreads();
    const int blk = blockIdx.y * GXL + blockIdx.x;
    if (tid < NR)
        part[blk * 32 + tid] = red[0][tid] + red[1][tid] + red[2][tid] + red[3][tid];
    __threadfence();       // release this block's partials
    __syncthreads();       // all fences done before ticket
    if (tid == 0) sticket = atomicAdd(done, 1);
    __syncthreads();
    if (sticket != NBLK - 1) return;

    // ---- finalize (last block) ----
    __threadfence();       // acquire
    if (tid < NR) {
        double s = 0.0;
#pragma unroll 8
        for (int b = 0; b < NBLK; ++b) s += (double)part[b * 32 + tid];
        fin[tid] = s;
    }
    __syncthreads();
    if (tid == 0) {
        const long long nTt = cnts[0], nNt = cnts[1];
        double acc = 0.0; int ngv = 0;
        for (int g = 0; g < NG; ++g) {
            const long long cT = cnts[2 + g], cN = cnts[2 + NG + g];
            const long long c0 = cT * cN;
            const long long c1 = (nTt - cT) * cN;
            const long long c2 = cT * (nNt - cN);
            const double t0 = fin[g]          / (double)(c0 > 0 ? c0 : 1);
            const double t1 = fin[NG + g]     / (double)(c1 > 0 ? c1 : 1);
            const double t2 = fin[2 * NG + g] / (double)(c2 > 0 ? c2 : 1);
            const int nv = (c0 > 0) + (c1 > 0) + (c2 > 0);
            const double gl = ((c0 > 0 ? t0 : 0.0) + (c1 > 0 ? t1 : 0.0) +
                               (c2 > 0 ? t2 : 0.0)) / (double)(nv > 0 ? nv : 1);
            if (nv > 0) { const double g2 = gl * gl; acc += g2 * g2; ++ngv; }
        }
        const double mean_p = acc / (double)(ngv > 0 ? ngv : 1);
        const double loss = pow(mean_p, 0.25);
        out[0] = (float)(ngv > 0 ? loss : 0.0);
    }
}

extern "C" void kernel_launch(void* const* d_in, const int* in_sizes, int n_in,
                              void* d_out, int out_size, void* d_ws, size_t ws_size,
                              hipStream_t stream) {
    const float* logits = (const float*)d_in[0];
    const float* ytox   = (const float*)d_in[1];
    const float* yid    = (const float*)d_in[2];
    const int B = in_sizes[0];

    char* ws = (char*)d_ws;
    int*    cnts = (int*)ws;                         // 20 ints
    int*    done = (int*)(ws + 128);                 // ticket
    float*  part = (float*)(ws + 512);               // NBLK x 32 floats = 32 KB
    char*   arr  = ws + 512 + NBLK * 32 * sizeof(float);
    float*  Tlog  = (float*)arr;
    int*    Tmask = (int*)(arr + 4 * (size_t)B);
    float*  Nlog  = (float*)(arr + 8 * (size_t)B);
    int*    Nmask = (int*)(arr + 12 * (size_t)B);

    hipMemsetAsync(ws, 0, 512, stream);              // zero cnts + done

    k_prep<<<dim3((B + 255) / 256), dim3(256), 0, stream>>>(
        logits, ytox, yid, B, Tlog, Tmask, Nlog, Nmask, cnts);

    k_main<<<dim3(GXL, GY), dim3(256), 0, stream>>>(
        Tlog, Tmask, Nlog, Nmask, cnts, part, done, (float*)d_out);
}

// Round 4
// 108.678 us; speedup vs baseline: 1.7950x; 1.7274x over previous
//
#include <hip/hip_runtime.h>
#include <math.h>

#define NG 9
#define GX 8            // i-chunks (8192/8 = 1024 raw rows each)
#define GY 64           // j-chunks (8192/64 = 128 raw rows each)
#define NBLK (GX * GY)  // 512 blocks = 2/CU
#define ROWS 48         // 27 sums + 9 cN + 9 cT + nN + nT + pad
#define IBMAX 4         // i slots per thread (covers nI <= 1024)

__device__ __forceinline__ float softplus_f(float x) {
    // stable: max(x,0) + log1p(exp(-|x|))
    float e = __expf(-fabsf(x));
    return fmaxf(x, 0.f) + __logf(1.f + e);
}

// Single fused kernel: classify + compact (LDS, ballot) + pairs + per-block partials.
// part layout is r-major: part[r*NBLK + blk]  (coalesced for the finalize kernel).
// No workspace zeroing needed: every block writes all its ROWS slots unconditionally.
__global__ __launch_bounds__(256, 2) void k_main(
    const float* __restrict__ logits, const float* __restrict__ ytox,
    const float* __restrict__ yid, int B, float* __restrict__ part) {

    __shared__ float iL[1024];
    __shared__ int   iM[1024];
    __shared__ float jL[256];
    __shared__ int   jM[256];
    __shared__ int   swcnt[4], swoff[4];
    __shared__ int   sbase;
    __shared__ int   scT[4][NG], scN[4][NG];
    __shared__ float red[4][27];

    const int tid = threadIdx.x, lane = tid & 63, wave = tid >> 6;
    const int IRAW = (B + GX - 1) / GX;
    const int JRAW = (B + GY - 1) / GY;

    if (tid < 4 * NG) { scT[tid / NG][tid % NG] = 0; scN[tid / NG][tid % NG] = 0; }
    if (tid == 0) sbase = 0;
    __syncthreads();

    // ---- Phase A: compact toxic i's of this block's x-chunk into LDS ----
    const int ibase0 = blockIdx.x * IRAW;
    for (int r0 = 0; r0 < IRAW; r0 += 256) {      // uniform trip count
        const int row = ibase0 + r0 + tid;
        const bool valid = (r0 + tid < IRAW) && (row < B);
        float l = 0.f; bool tox = false; int m = 0;
        if (valid) {
            l = logits[row];
            tox = ytox[row] >= 0.5f;
#pragma unroll
            for (int g = 0; g < NG; ++g)
                if (yid[row * NG + g] >= 0.5f) m |= 1 << g;
        }
        const unsigned long long bal = __ballot(tox);
        const int pos = __popcll(bal & ((1ull << lane) - 1ull));
        if (lane == 0) swcnt[wave] = __popcll(bal);
#pragma unroll
        for (int g = 0; g < NG; ++g) {
            const unsigned long long bg = __ballot(tox && ((m >> g) & 1));
            if (lane == 0) scT[wave][g] += __popcll(bg);
        }
        __syncthreads();
        if (tid == 0) {
            int b = sbase;
#pragma unroll
            for (int w = 0; w < 4; ++w) { swoff[w] = b; b += swcnt[w]; }
            sbase = b;
        }
        __syncthreads();
        if (tox) { const int p = swoff[wave] + pos; iL[p] = l; iM[p] = m; }
    }
    __syncthreads();
    const int nI = sbase;
    __syncthreads();

    // ---- Phase B: compact non-toxic j's of this block's y-chunk into LDS ----
    const int jbase0 = blockIdx.y * JRAW;
    {
        const int row = jbase0 + tid;
        const bool valid = (tid < JRAW) && (row < B);
        float l = 0.f; bool nt = false; int m = 0;
        if (valid) {
            l = logits[row];
            nt = ytox[row] < 0.5f;
#pragma unroll
            for (int g = 0; g < NG; ++g)
                if (yid[row * NG + g] >= 0.5f) m |= 1 << g;
        }
        const unsigned long long bal = __ballot(nt);
        const int pos = __popcll(bal & ((1ull << lane) - 1ull));
        if (lane == 0) swcnt[wave] = __popcll(bal);
#pragma unroll
        for (int g = 0; g < NG; ++g) {
            const unsigned long long bg = __ballot(nt && ((m >> g) & 1));
            if (lane == 0) scN[wave][g] += __popcll(bg);
        }
        __syncthreads();
        if (tid == 0) {
            int b = 0;
#pragma unroll
            for (int w = 0; w < 4; ++w) { swoff[w] = b; b += swcnt[w]; }
            sbase = b;
        }
        __syncthreads();
        if (nt) { const int p = swoff[wave] + pos; jL[p] = l; jM[p] = m; }
    }
    __syncthreads();
    const int nJ = sbase;

    // ---- Phase C: pair loop (IB=4 i's per thread, j broadcast from LDS) ----
    float li[IBMAX]; int mi[IBMAX];
#pragma unroll
    for (int u = 0; u < IBMAX; ++u) {
        const int k = tid + 256 * u;
        const bool a = k < nI;
        li[u] = a ? iL[k] : 0.f;
        mi[u] = a ? iM[k] : 0;
    }
    float Rall[IBMAX];
    float Rg[IBMAX][NG];
#pragma unroll
    for (int u = 0; u < IBMAX; ++u) {
        Rall[u] = 0.f;
#pragma unroll
        for (int g = 0; g < NG; ++g) Rg[u][g] = 0.f;
    }

#pragma unroll 2
    for (int k = 0; k < nJ; ++k) {
        const float lj = jL[k];                                   // LDS broadcast
        const int   mj = __builtin_amdgcn_readfirstlane(jM[k]);   // uniform -> SGPR
        float s[IBMAX];
#pragma unroll
        for (int u = 0; u < IBMAX; ++u) {
            s[u] = softplus_f(lj - li[u]);    // 4 independent trans chains
            Rall[u] += s[u];
        }
#pragma unroll
        for (int g = 0; g < NG; ++g) {
            const float bg = ((mj >> g) & 1) ? 1.0f : 0.0f;       // scalar cselect
#pragma unroll
            for (int u = 0; u < IBMAX; ++u)
                Rg[u][g] = fmaf(bg, s[u], Rg[u][g]);
        }
    }

    // ---- Phase D: fold + block reduction of the 27 sum rows ----
#pragma unroll
    for (int g = 0; g < NG; ++g) {
        float x0 = 0.f, x1 = 0.f, x2 = 0.f;
#pragma unroll
        for (int u = 0; u < IBMAX; ++u) {
            const bool a = (tid + 256 * u) < nI;
            const float rg = a ? Rg[u][g] : 0.f;
            const float ra = a ? Rall[u] : 0.f;
            const bool ing = (mi[u] >> g) & 1;
            x0 += (a && ing) ? rg : 0.f;          // t=0: i in Tg, j in Ng
            x1 += (a && !ing) ? rg : 0.f;         // t=1: i toxic !in g, j in Ng
            x2 += (a && ing) ? (ra - rg) : 0.f;   // t=2: i in Tg, j !in Ng
        }
#pragma unroll
        for (int off = 32; off > 0; off >>= 1) {
            x0 += __shfl_xor(x0, off, 64);
            x1 += __shfl_xor(x1, off, 64);
            x2 += __shfl_xor(x2, off, 64);
        }
        if (lane == 0) { red[wave][g] = x0; red[wave][NG + g] = x1; red[wave][2 * NG + g] = x2; }
    }
    __syncthreads();
    const int blk = blockIdx.y * GX + blockIdx.x;
    if (tid < 27)
        part[tid * NBLK + blk] = red[0][tid] + red[1][tid] + red[2][tid] + red[3][tid];
    if (tid == 0) {   // count rows: block-scalar, no reduction needed
#pragma unroll
        for (int g = 0; g < NG; ++g) {
            const float cn = (blockIdx.x == 0)
                ? (float)(scN[0][g] + scN[1][g] + scN[2][g] + scN[3][g]) : 0.f;
            const float ct = (blockIdx.y == 0)
                ? (float)(scT[0][g] + scT[1][g] + scT[2][g] + scT[3][g]) : 0.f;
            part[(27 + g) * NBLK + blk] = cn;
            part[(36 + g) * NBLK + blk] = ct;
        }
        part[45 * NBLK + blk] = (blockIdx.x == 0) ? (float)nJ : 0.f;
        part[46 * NBLK + blk] = (blockIdx.y == 0) ? (float)nI : 0.f;
        part[47 * NBLK + blk] = 0.f;
    }
}

// Finalize: 8 waves x 6 rows, coalesced loads, then scalar fp64 epilogue.
__global__ __launch_bounds__(512) void k_final(
    const float* __restrict__ part, float* __restrict__ out) {
    __shared__ float fin[ROWS];
    const int tid = threadIdx.x, lane = tid & 63, wave = tid >> 6;
#pragma unroll
    for (int rr = 0; rr < 6; ++rr) {
        const int r = wave * 6 + rr;
        float s = 0.f;
#pragma unroll
        for (int q = 0; q < NBLK / 64; ++q)
            s += part[r * NBLK + q * 64 + lane];
#pragma unroll
        for (int off = 32; off > 0; off >>= 1) s += __shfl_xor(s, off, 64);
        if (lane == 0) fin[r] = s;
    }
    __syncthreads();
    if (tid == 0) {
        const long long nT = (long long)(fin[46] + 0.5f);
        const long long nN = (long long)(fin[45] + 0.5f);
        double acc = 0.0; int ngv = 0;
        for (int g = 0; g < NG; ++g) {
            const long long cT = (long long)(fin[36 + g] + 0.5f);
            const long long cN = (long long)(fin[27 + g] + 0.5f);
            const long long c0 = cT * cN;
            const long long c1 = (nT - cT) * cN;
            const long long c2 = cT * (nN - cN);
            const double t0 = (double)fin[g]          / (double)(c0 > 0 ? c0 : 1);
            const double t1 = (double)fin[NG + g]     / (double)(c1 > 0 ? c1 : 1);
            const double t2 = (double)fin[2 * NG + g] / (double)(c2 > 0 ? c2 : 1);
            const int nv = (c0 > 0) + (c1 > 0) + (c2 > 0);
            const double gl = ((c0 > 0 ? t0 : 0.0) + (c1 > 0 ? t1 : 0.0) +
                               (c2 > 0 ? t2 : 0.0)) / (double)(nv > 0 ? nv : 1);
            if (nv > 0) { const double g2 = gl * gl; acc += g2 * g2; ++ngv; }
        }
        const double mp = acc / (double)(ngv > 0 ? ngv : 1);
        const double loss = sqrt(sqrt(mp));   // ^(1/4), cheaper than pow
        out[0] = (float)(ngv > 0 ? loss : 0.0);
    }
}

extern "C" void kernel_launch(void* const* d_in, const int* in_sizes, int n_in,
                              void* d_out, int out_size, void* d_ws, size_t ws_size,
                              hipStream_t stream) {
    const float* logits = (const float*)d_in[0];
    const float* ytox   = (const float*)d_in[1];
    const float* yid    = (const float*)d_in[2];
    const int B = in_sizes[0];
    float* part = (float*)d_ws;   // ROWS x NBLK floats = 96 KB, no zeroing needed

    k_main<<<dim3(GX, GY), dim3(256), 0, stream>>>(logits, ytox, yid, B, part);
    k_final<<<dim3(1), dim3(512), 0, stream>>>(part, (float*)d_out);
}